// Round 13
// baseline (101.046 us; speedup 1.0000x reference)
//
#include <hip/hip_runtime.h>
#include <hip/hip_bf16.h>
#include <math.h>

// Problem constants (B=8, N=1025, D=64 per reference setup_inputs)
#define NN 1025
#define DD 64
#define T_ROWS 8192                       // 8 * 1024
#define C_EXP 28.85390081777927f          // 20 * log2(e)
#define EXP_NEG20 2.0611536224385583e-9f  // e^-20
#define LN2 0.6931471805599453f
#define JC_SLABS 32

typedef _Float16 h8 __attribute__((ext_vector_type(8)));
typedef float f4 __attribute__((ext_vector_type(4)));

// ws layout (bytes):
//   qh   : _Float16[8192*64] @ 0         = qhat * C_EXP
//   kh   : _Float16[8192*64] @ 0x100000  = khat
//   diag : float[8192]       @ 0x200000  = 20*dot(qhat_i, khat_i)
//   scale: float[8192]       @ +32KB     = valid_j ? e^-20 : 0
//   sp   : float[32][8192]   @ +64KB     = per-jc-slab row partials
//          (slab-major: block (ib,jc) stores 256 CONTIGUOUS floats --
//           R9's failure was the transposed layout: 4B-per-128B scatter)
#define OFF_QH   0
#define OFF_KH   (1 << 20)
#define OFF_DIAG (2 << 20)

// ---------------------------------------------------------------------------
// Prep: L2-normalize, stage f16 (Q pre-scaled by 20*log2e), exact fp32 diag,
// multiplicative mask. One wave per row. (No accumulator zeroing needed:
// sp is fully written by logits.)
// ---------------------------------------------------------------------------
__global__ __launch_bounds__(256) void prep_kernel(
    const float* __restrict__ outE, const float* __restrict__ tgtE,
    const int* __restrict__ mask, char* wsb)
{
    _Float16* qh = (_Float16*)(wsb + OFF_QH);
    _Float16* kh = (_Float16*)(wsb + OFF_KH);
    float* diag  = (float*)(wsb + OFF_DIAG);
    float* scale = diag + T_ROWS;

    int wid  = threadIdx.x >> 6;
    int lane = threadIdx.x & 63;
    int t = blockIdx.x * 4 + wid;
    int b = t >> 10, n = t & 1023;
    float qv = outE[(size_t)(b * NN + n) * DD + lane];
    float kv = tgtE[(size_t)(b * NN + n + 1) * DD + lane];
    float qs = qv * qv, ks = kv * kv;
    #pragma unroll
    for (int m = 32; m; m >>= 1) {
        qs += __shfl_xor(qs, m, 64);
        ks += __shfl_xor(ks, m, 64);
    }
    float qn  = qv * (1.0f / fmaxf(sqrtf(qs), 1e-12f));
    float knv = kv * (1.0f / fmaxf(sqrtf(ks), 1e-12f));
    qh[(size_t)t * DD + lane] = (_Float16)(qn * C_EXP);
    kh[(size_t)t * DD + lane] = (_Float16)knv;
    float dt = qn * knv;
    #pragma unroll
    for (int m = 32; m; m >>= 1) dt += __shfl_xor(dt, m, 64);
    if (lane == 0) {
        diag[t]  = 20.0f * dt;
        scale[t] = mask[b * NN + n + 1] ? EXP_NEG20 : 0.0f;
    }
}

// ---------------------------------------------------------------------------
// Logits — R11 body (proven best: 256x256 tile, 4 blocks/CU, XOR-swizzled
// LDS K-chunk, m89 16x16x32 layout) with ONE change: the 262144 contended
// device-scope atomicAdds (measured: 4 MB memory-side writes, prime stall
// suspect) are replaced by exclusive CONTIGUOUS float4 partial stores
// sp[jc][row] — each block writes a dense 1 KB run, written exactly once.
// ---------------------------------------------------------------------------
__global__ __launch_bounds__(256, 4) void logits_kernel(char* wsb)
{
    const _Float16* qh = (const _Float16*)(wsb + OFF_QH);
    const _Float16* kh = (const _Float16*)(wsb + OFF_KH);
    const float* diag_ = (const float*)(wsb + OFF_DIAG);
    const float* scale = diag_ + T_ROWS;
    float* sp = (float*)(wsb + OFF_DIAG) + 2 * T_ROWS;

    __shared__ __align__(16) char kbuf[32768];   // 256 rows x 128 B, swizzled
    __shared__ float sbuf[256];

    int tid  = threadIdx.x;
    int ib = blockIdx.x >> 5;   // 32 i-blocks of 256 rows
    int jc = blockIdx.x & 31;   // 32 j-chunks of 256 cols
    int wid  = tid >> 6;
    int lane = tid & 63;
    int i0 = ib * 256 + wid * 64;
    int j0base = jc * 256;
    int r16 = lane & 15;          // A-row / B-col within 16x16 tile
    int g   = lane >> 4;          // k-group 0..3
    int ko  = g * 8;              // f16 k offset within K=32 chunk

    // Q fragments (wave-private rows) — loop-invariant, stay in VGPRs.
    h8 qf[4][2];
    #pragma unroll
    for (int m = 0; m < 4; ++m)
        #pragma unroll
        for (int kk = 0; kk < 2; ++kk)
            qf[m][kk] = *(const h8*)(qh + (size_t)(i0 + m * 16 + r16) * DD + kk * 32 + ko);

    // Stage K chunk into LDS, swizzled: LDS[o ^ ((row&7)<<4)] = G[o].
    {
        const char* ksrc = (const char*)(kh + (size_t)j0base * DD);
        #pragma unroll
        for (int is = 0; is < 8; ++is) {
            int o = is * 4096 + tid * 16;
            int f = o ^ (((o >> 7) & 7) << 4);
            *(float4*)(kbuf + f) = *(const float4*)(ksrc + o);
        }
        sbuf[tid] = scale[j0base + tid];
    }
    __syncthreads();

    float acc[4][4];
    #pragma unroll
    for (int m = 0; m < 4; ++m)
        #pragma unroll
        for (int r = 0; r < 4; ++r) acc[m][r] = 0.0f;

    #pragma unroll 4
    for (int jt = 0; jt < 16; ++jt) {
        int row = jt * 16 + r16;
        int sw  = (row & 7) << 4;
        float sc = sbuf[jt * 16 + r16];
        h8 kf0 = *(const h8*)(kbuf + row * 128 + ((g * 16) ^ sw));
        h8 kf1 = *(const h8*)(kbuf + row * 128 + ((64 + g * 16) ^ sw));
        #pragma unroll
        for (int m = 0; m < 4; ++m) {
            f4 c = {0.f, 0.f, 0.f, 0.f};
            c = __builtin_amdgcn_mfma_f32_16x16x32_f16(qf[m][0], kf0, c, 0, 0, 0);
            c = __builtin_amdgcn_mfma_f32_16x16x32_f16(qf[m][1], kf1, c, 0, 0, 0);
            #pragma unroll
            for (int r = 0; r < 4; ++r)
                acc[m][r] += __builtin_amdgcn_exp2f(c[r]) * sc;
        }
    }

    // Reduce across the 16 col-lanes (same output row), then one float4
    // plain store per (lane, m): rows rbase..rbase+3 are consecutive.
    #pragma unroll
    for (int msk = 1; msk < 16; msk <<= 1)
        #pragma unroll
        for (int m = 0; m < 4; ++m)
            #pragma unroll
            for (int r = 0; r < 4; ++r)
                acc[m][r] += __shfl_xor(acc[m][r], msk, 64);

    if (r16 == 0) {
        float* dst = sp + (size_t)jc * T_ROWS + i0 + g * 4;
        #pragma unroll
        for (int m = 0; m < 4; ++m) {
            f4 v = {acc[m][0], acc[m][1], acc[m][2], acc[m][3]};
            *(f4*)(dst + m * 16) = v;
        }
    }
}

// ---------------------------------------------------------------------------
// Loss: one block, 1024 threads, 8 rows each. Per row: sum the 32 slab
// partials (slab-major -> consecutive threads read consecutive addresses,
// fully coalesced; 1 MB of L2-resident reads). HW log2 for ln.
// ---------------------------------------------------------------------------
__global__ __launch_bounds__(1024) void loss_kernel(const char* __restrict__ wsb,
                                                    float* __restrict__ out)
{
    const float* diag  = (const float*)(wsb + OFF_DIAG);
    const float* scale = diag + T_ROWS;
    const float* sp    = scale + T_ROWS;

    int tid = threadIdx.x;
    int wid = tid >> 6, lane = tid & 63;

    float sv[8];
    #pragma unroll
    for (int r = 0; r < 8; ++r) sv[r] = 0.f;
    for (int c = 0; c < JC_SLABS; ++c) {
        const float* slab = sp + (size_t)c * T_ROWS;
        #pragma unroll
        for (int r = 0; r < 8; ++r)
            sv[r] += slab[tid + 1024 * r];
    }

    float num = 0.f, den = 0.f;
    #pragma unroll
    for (int r = 0; r < 8; ++r) {
        int t = tid + 1024 * r;
        if (scale[t] != 0.0f) {
            num += diag[t] - 20.0f - __builtin_amdgcn_logf(sv[r]) * LN2;
            den += 1.0f;
        }
    }
    #pragma unroll
    for (int m = 32; m; m >>= 1) {
        num += __shfl_xor(num, m, 64);
        den += __shfl_xor(den, m, 64);
    }
    __shared__ float sn[16], sd[16];
    if (lane == 0) { sn[wid] = num; sd[wid] = den; }
    __syncthreads();
    if (tid == 0) {
        float tn = 0.f, td = 0.f;
        #pragma unroll
        for (int i = 0; i < 16; ++i) { tn += sn[i]; td += sd[i]; }
        out[0] = -tn / td;
    }
}

extern "C" void kernel_launch(void* const* d_in, const int* in_sizes, int n_in,
                              void* d_out, int out_size, void* d_ws, size_t ws_size,
                              hipStream_t stream) {
    const float* outE = (const float*)d_in[0];
    const float* tgtE = (const float*)d_in[1];
    const int*   mask = (const int*)d_in[2];
    char* wsb = (char*)d_ws;
    float* out = (float*)d_out;

    prep_kernel<<<T_ROWS / 4, 256, 0, stream>>>(outE, tgtE, mask, wsb);
    logits_kernel<<<32 * 32, 256, 0, stream>>>(wsb);
    loss_kernel<<<1, 1024, 0, stream>>>(wsb, out);
}

// Round 16
// 80.479 us; speedup vs baseline: 1.2555x; 1.2555x over previous
//
#include <hip/hip_runtime.h>
#include <hip/hip_bf16.h>
#include <math.h>

// Problem constants (B=8, N=1025, D=64 per reference setup_inputs)
#define NN 1025
#define DD 64
#define T_ROWS 8192                       // 8 * 1024
#define C_EXP 28.85390081777927f          // 20 * log2(e)
#define EXP_NEG20 2.0611536224385583e-9f  // e^-20
#define LN2 0.6931471805599453f
#define JC_SLABS 32
#define LOSS_BLOCKS 32

typedef _Float16 h8 __attribute__((ext_vector_type(8)));
typedef float f4 __attribute__((ext_vector_type(4)));

// ws layout (bytes):
//   qh   : _Float16[8192*64] @ 0         = qhat * C_EXP
//   kh   : _Float16[8192*64] @ 0x100000  = khat
//   f32 region @ 0x200000 (float offsets):
//     diag [0, 8192)        = 20*dot(qhat_i, khat_i)
//     scale[8192, 16384)    = valid_j ? e^-20 : 0
//     sp   [16384, 278528)  = float[32][8192] per-jc-slab row partials
//                             (slab-major: contiguous 1KB runs per block)
//     accum[278528, 278530) = (num, den)
//     cnt  @ 278530         = finished-block counter (unsigned)
#define OFF_QH   0
#define OFF_KH   (1 << 20)
#define OFF_DIAG (2 << 20)
#define SP_OFF   16384
#define ACC_OFF  278528

// ---------------------------------------------------------------------------
// Prep: L2-normalize, stage f16 (Q pre-scaled by 20*log2e), exact fp32 diag,
// multiplicative mask; zero accum + counter. One wave per row.
// ---------------------------------------------------------------------------
__global__ __launch_bounds__(256) void prep_kernel(
    const float* __restrict__ outE, const float* __restrict__ tgtE,
    const int* __restrict__ mask, char* wsb)
{
    _Float16* qh = (_Float16*)(wsb + OFF_QH);
    _Float16* kh = (_Float16*)(wsb + OFF_KH);
    float* fbase = (float*)(wsb + OFF_DIAG);
    float* diag  = fbase;
    float* scale = fbase + T_ROWS;

    int wid  = threadIdx.x >> 6;
    int lane = threadIdx.x & 63;
    int t = blockIdx.x * 4 + wid;
    int b = t >> 10, n = t & 1023;
    float qv = outE[(size_t)(b * NN + n) * DD + lane];
    float kv = tgtE[(size_t)(b * NN + n + 1) * DD + lane];
    float qs = qv * qv, ks = kv * kv;
    #pragma unroll
    for (int m = 32; m; m >>= 1) {
        qs += __shfl_xor(qs, m, 64);
        ks += __shfl_xor(ks, m, 64);
    }
    float qn  = qv * (1.0f / fmaxf(sqrtf(qs), 1e-12f));
    float knv = kv * (1.0f / fmaxf(sqrtf(ks), 1e-12f));
    qh[(size_t)t * DD + lane] = (_Float16)(qn * C_EXP);
    kh[(size_t)t * DD + lane] = (_Float16)knv;
    float dt = qn * knv;
    #pragma unroll
    for (int m = 32; m; m >>= 1) dt += __shfl_xor(dt, m, 64);
    if (lane == 0) {
        diag[t]  = 20.0f * dt;
        scale[t] = mask[b * NN + n + 1] ? EXP_NEG20 : 0.0f;
        if (t == 0) {
            fbase[ACC_OFF]     = 0.0f;
            fbase[ACC_OFF + 1] = 0.0f;
            *(unsigned*)(fbase + ACC_OFF + 2) = 0u;
        }
    }
}

// ---------------------------------------------------------------------------
// Logits — byte-identical to R13 (256x256 tile, 4 blocks/CU, XOR-swizzled
// LDS K-chunk, m89 16x16x32 layout, exclusive contiguous float4 partial
// stores sp[jc][row]).
// ---------------------------------------------------------------------------
__global__ __launch_bounds__(256, 4) void logits_kernel(char* wsb)
{
    const _Float16* qh = (const _Float16*)(wsb + OFF_QH);
    const _Float16* kh = (const _Float16*)(wsb + OFF_KH);
    const float* scale = (const float*)(wsb + OFF_DIAG) + T_ROWS;
    float* sp = (float*)(wsb + OFF_DIAG) + SP_OFF;

    __shared__ __align__(16) char kbuf[32768];   // 256 rows x 128 B, swizzled
    __shared__ float sbuf[256];

    int tid  = threadIdx.x;
    int ib = blockIdx.x >> 5;   // 32 i-blocks of 256 rows
    int jc = blockIdx.x & 31;   // 32 j-chunks of 256 cols
    int wid  = tid >> 6;
    int lane = tid & 63;
    int i0 = ib * 256 + wid * 64;
    int j0base = jc * 256;
    int r16 = lane & 15;          // A-row / B-col within 16x16 tile
    int g   = lane >> 4;          // k-group 0..3
    int ko  = g * 8;              // f16 k offset within K=32 chunk

    // Q fragments (wave-private rows) — loop-invariant, stay in VGPRs.
    h8 qf[4][2];
    #pragma unroll
    for (int m = 0; m < 4; ++m)
        #pragma unroll
        for (int kk = 0; kk < 2; ++kk)
            qf[m][kk] = *(const h8*)(qh + (size_t)(i0 + m * 16 + r16) * DD + kk * 32 + ko);

    // Stage K chunk into LDS, swizzled: LDS[o ^ ((row&7)<<4)] = G[o].
    {
        const char* ksrc = (const char*)(kh + (size_t)j0base * DD);
        #pragma unroll
        for (int is = 0; is < 8; ++is) {
            int o = is * 4096 + tid * 16;
            int f = o ^ (((o >> 7) & 7) << 4);
            *(float4*)(kbuf + f) = *(const float4*)(ksrc + o);
        }
        sbuf[tid] = scale[j0base + tid];
    }
    __syncthreads();

    float acc[4][4];
    #pragma unroll
    for (int m = 0; m < 4; ++m)
        #pragma unroll
        for (int r = 0; r < 4; ++r) acc[m][r] = 0.0f;

    #pragma unroll 4
    for (int jt = 0; jt < 16; ++jt) {
        int row = jt * 16 + r16;
        int sw  = (row & 7) << 4;
        float sc = sbuf[jt * 16 + r16];
        h8 kf0 = *(const h8*)(kbuf + row * 128 + ((g * 16) ^ sw));
        h8 kf1 = *(const h8*)(kbuf + row * 128 + ((64 + g * 16) ^ sw));
        #pragma unroll
        for (int m = 0; m < 4; ++m) {
            f4 c = {0.f, 0.f, 0.f, 0.f};
            c = __builtin_amdgcn_mfma_f32_16x16x32_f16(qf[m][0], kf0, c, 0, 0, 0);
            c = __builtin_amdgcn_mfma_f32_16x16x32_f16(qf[m][1], kf1, c, 0, 0, 0);
            #pragma unroll
            for (int r = 0; r < 4; ++r)
                acc[m][r] += __builtin_amdgcn_exp2f(c[r]) * sc;
        }
    }

    // Reduce across the 16 col-lanes (same output row), then one float4
    // plain store per (lane, m): rows rbase..rbase+3 are consecutive.
    #pragma unroll
    for (int msk = 1; msk < 16; msk <<= 1)
        #pragma unroll
        for (int m = 0; m < 4; ++m)
            #pragma unroll
            for (int r = 0; r < 4; ++r)
                acc[m][r] += __shfl_xor(acc[m][r], msk, 64);

    if (r16 == 0) {
        float* dst = sp + (size_t)jc * T_ROWS + i0 + g * 4;
        #pragma unroll
        for (int m = 0; m < 4; ++m) {
            f4 v = {acc[m][0], acc[m][1], acc[m][2], acc[m][3]};
            *(f4*)(dst + m * 16) = v;
        }
    }
}

// ---------------------------------------------------------------------------
// Loss: 32 blocks x 256 threads, one row per thread (R13 failure: a SINGLE
// block serially chained 1 MB of cross-XCD loads ~ +15 µs; now 32 blocks
// read coalesced slab segments in parallel). Per-block (num,den) ->
// 2 device atomicAdds; last block finalizes out = -num/den.
// ---------------------------------------------------------------------------
__global__ __launch_bounds__(256) void loss_kernel(char* wsb, float* __restrict__ out)
{
    float* fbase = (float*)(wsb + OFF_DIAG);
    const float* diag  = fbase;
    const float* scale = fbase + T_ROWS;
    const float* sp    = fbase + SP_OFF;
    float* accum       = fbase + ACC_OFF;
    unsigned* cnt      = (unsigned*)(fbase + ACC_OFF + 2);

    int tid = threadIdx.x;
    int wid = tid >> 6, lane = tid & 63;
    int t = blockIdx.x * 256 + tid;

    float sv = 0.f;
    #pragma unroll 8
    for (int c = 0; c < JC_SLABS; ++c)
        sv += sp[(size_t)c * T_ROWS + t];   // coalesced: tid-consecutive

    float num = 0.f, den = 0.f;
    if (scale[t] != 0.0f) {
        num = diag[t] - 20.0f - __builtin_amdgcn_logf(sv) * LN2;
        den = 1.0f;
    }
    #pragma unroll
    for (int m = 32; m; m >>= 1) {
        num += __shfl_xor(num, m, 64);
        den += __shfl_xor(den, m, 64);
    }
    __shared__ float sn[4], sd[4];
    if (lane == 0) { sn[wid] = num; sd[wid] = den; }
    __syncthreads();

    __shared__ unsigned is_last;
    if (tid == 0) {
        atomicAdd(&accum[0], sn[0] + sn[1] + sn[2] + sn[3]);
        atomicAdd(&accum[1], sd[0] + sd[1] + sd[2] + sd[3]);
        __threadfence();
        is_last = (atomicAdd(cnt, 1u) == LOSS_BLOCKS - 1) ? 1u : 0u;
    }
    __syncthreads();
    if (is_last && tid == 0) {
        float tn = __hip_atomic_load(&accum[0], __ATOMIC_RELAXED,
                                     __HIP_MEMORY_SCOPE_AGENT);
        float td = __hip_atomic_load(&accum[1], __ATOMIC_RELAXED,
                                     __HIP_MEMORY_SCOPE_AGENT);
        out[0] = -tn / td;
    }
}

extern "C" void kernel_launch(void* const* d_in, const int* in_sizes, int n_in,
                              void* d_out, int out_size, void* d_ws, size_t ws_size,
                              hipStream_t stream) {
    const float* outE = (const float*)d_in[0];
    const float* tgtE = (const float*)d_in[1];
    const int*   mask = (const int*)d_in[2];
    char* wsb = (char*)d_ws;
    float* out = (float*)d_out;

    prep_kernel<<<T_ROWS / 4, 256, 0, stream>>>(outE, tgtE, mask, wsb);
    logits_kernel<<<32 * 32, 256, 0, stream>>>(wsb);
    loss_kernel<<<LOSS_BLOCKS, 256, 0, stream>>>(wsb, out);
}